// Round 1
// baseline (114.799 us; speedup 1.0000x reference)
//
#include <hip/hip_runtime.h>
#include <hip/hip_bf16.h>

typedef __attribute__((ext_vector_type(8))) short short8;   // 8 x bf16 bits = 4 VGPRs
typedef __attribute__((ext_vector_type(4))) float f32x4;
typedef __attribute__((ext_vector_type(2))) float f32x2;
typedef __attribute__((ext_vector_type(4))) unsigned uint4v;

#define NW 8            // waves per block
#define BPW 16          // batches per wave
#define BPB (NW * BPW)  // 128 batches per block

static __device__ __forceinline__ unsigned pk_bf16(float a, float b) {
    unsigned d;
    asm("v_cvt_pk_bf16_f32 %0, %1, %2" : "=v"(d) : "v"(a), "v"(b));
    return d;
}

// manual RNE pack with *known* bit placement (lo16 <- x, hi16 <- y)
static __device__ __forceinline__ unsigned rne_bf16_pair(float x, float y) {
    unsigned ux = __float_as_uint(x), uy = __float_as_uint(y);
    ux = (ux + 0x7fffu + ((ux >> 16) & 1u)) >> 16;
    uy = (uy + 0x7fffu + ((uy >> 16) & 1u)) >> 16;
    return ux | (uy << 16);
}

static __device__ __forceinline__ short8 pack_frag(f32x4 a, f32x4 b) {
    union { unsigned u[4]; short8 s; } u;
    u.u[0] = pk_bf16(a.x, a.y);
    u.u[1] = pk_bf16(a.z, a.w);
    u.u[2] = pk_bf16(b.x, b.y);
    u.u[3] = pk_bf16(b.z, b.w);
    return u.s;
}

// Stage B-operand fragments of W^T (B[k][n] = W[n][k_off + k]) into LDS in
// fragment order: entry idx = (kt*nct + ct)*64 + lane; lane holds 8 bf16 with
// k = kt*32 + (lane>>4)*8 + j, n = ct*16 + (lane&15).
static __device__ __forceinline__ void stage_bfrags(const float* __restrict__ w,
                                                    int row_stride, int k_off, int nct,
                                                    short8* lds, int tid) {
    const int total = 4 * nct * 64;
    for (int idx = tid; idx < total; idx += NW * 64) {
        int lane = idx & 63;
        int ct = (idx >> 6) % nct;
        int kt = idx / (64 * nct);
        int n = ct * 16 + (lane & 15);
        int k = kt * 32 + (lane >> 4) * 8;
        const float* p = w + (size_t)n * row_stride + k_off + k;
        f32x4 a = *(const f32x4*)p;
        f32x4 b = *(const f32x4*)(p + 4);
        lds[idx] = pack_frag(a, b);
    }
}

__global__ __launch_bounds__(NW * 64, 4)
void mask_attn_fused(const float* __restrict__ value, const float* __restrict__ key,
                     const int* __restrict__ seq_len, const float* __restrict__ w1,
                     const float* __restrict__ b1, const float* __restrict__ w2,
                     const float* __restrict__ fcw, const float* __restrict__ fcb,
                     float* __restrict__ out, int B) {
    __shared__ short8 wlds[2048];                        // 32 KiB (Wk -> Wv -> fcw, time-shared)
    __shared__ __align__(16) unsigned obuf[NW][16][64];  // 32 KiB (o vectors, bf16-packed)

    const int tid = threadIdx.x;
    const int wave = tid >> 6;
    const int lane = tid & 63;
    const int g = lane >> 4;   // 0..3
    const int lo = lane & 15;  // 0..15

    const long long b0w = (long long)blockIdx.x * BPB + (long long)wave * BPW;

    // ---------- phase 1: Wk fragments -> LDS ----------
    stage_bfrags(w1, 2 * 128, 0, 8, wlds, tid);
    __syncthreads();

    // ---------- phase 2: HK = b1 + key @ Wk^T for this wave's 16 batches ----------
    // C/D layout: row = (lane>>4)*4 + reg (= batch index), col = ct*16 + (lane&15)
    unsigned hkp[8][2];
    {
        long long kb = b0w + lo; if (kb > (long long)B - 1) kb = (long long)B - 1;
        const float* kp = key + kb * 128 + g * 8;
        short8 af[4];
#pragma unroll
        for (int kt = 0; kt < 4; ++kt)
            af[kt] = pack_frag(*(const f32x4*)(kp + kt * 32), *(const f32x4*)(kp + kt * 32 + 4));
        f32x4 hk[8];
#pragma unroll
        for (int ct = 0; ct < 8; ++ct) {
            float bv = b1[ct * 16 + lo];
            hk[ct] = (f32x4){bv, bv, bv, bv};
        }
#pragma unroll
        for (int kt = 0; kt < 4; ++kt)
#pragma unroll
            for (int ct = 0; ct < 8; ++ct)
                hk[ct] = __builtin_amdgcn_mfma_f32_16x16x32_bf16(
                    af[kt], wlds[(kt * 8 + ct) * 64 + lane], hk[ct], 0, 0, 0);
#pragma unroll
        for (int ct = 0; ct < 8; ++ct) {
            hkp[ct][0] = rne_bf16_pair(hk[ct].x, hk[ct].y);
            hkp[ct][1] = rne_bf16_pair(hk[ct].z, hk[ct].w);
        }
    }
    __syncthreads();

    // ---------- phase 3: Wv fragments -> LDS ----------
    stage_bfrags(w1, 2 * 128, 128, 8, wlds, tid);
    __syncthreads();

    float w2v[8];
#pragma unroll
    for (int ct = 0; ct < 8; ++ct) w2v[ct] = w2[ct * 16 + lo];

    // ---------- phase 4: per-l tile GEMM (rows = 16 batches) + weight extraction ----
    // After this, w_l[l] at each lane = raw attention logit of batch (b0w+lo), pos l.
    float w_l[9];
    {
        long long vb = b0w + lo; if (vb > (long long)B - 1) vb = (long long)B - 1;
        const float* ap = value + vb * (9 * 128) + g * 8;
#pragma unroll
        for (int l = 0; l < 9; ++l) {
            short8 af[4];
#pragma unroll
            for (int kt = 0; kt < 4; ++kt)
                af[kt] = pack_frag(*(const f32x4*)(ap + l * 128 + kt * 32),
                                   *(const f32x4*)(ap + l * 128 + kt * 32 + 4));
            f32x4 acc[8];
#pragma unroll
            for (int ct = 0; ct < 8; ++ct) {  // init C with hk (rows here = same batches)
                acc[ct].x = __uint_as_float(hkp[ct][0] << 16);
                acc[ct].y = __uint_as_float(hkp[ct][0] & 0xffff0000u);
                acc[ct].z = __uint_as_float(hkp[ct][1] << 16);
                acc[ct].w = __uint_as_float(hkp[ct][1] & 0xffff0000u);
            }
#pragma unroll
            for (int kt = 0; kt < 4; ++kt)
#pragma unroll
                for (int ct = 0; ct < 8; ++ct)
                    acc[ct] = __builtin_amdgcn_mfma_f32_16x16x32_bf16(
                        af[kt], wlds[(kt * 8 + ct) * 64 + lane], acc[ct], 0, 0, 0);
            // weight = sum_h relu(h) * w2[h]; per-lane partial over its 8 columns
            float p0 = 0.f, p1 = 0.f, p2 = 0.f, p3 = 0.f;
#pragma unroll
            for (int ct = 0; ct < 8; ++ct) {
                p0 += fmaxf(acc[ct].x, 0.f) * w2v[ct];
                p1 += fmaxf(acc[ct].y, 0.f) * w2v[ct];
                p2 += fmaxf(acc[ct].z, 0.f) * w2v[ct];
                p3 += fmaxf(acc[ct].w, 0.f) * w2v[ct];
            }
#pragma unroll
            for (int m = 1; m <= 8; m <<= 1) {  // reduce across 16-lane column groups
                p0 += __shfl_xor(p0, m);
                p1 += __shfl_xor(p1, m);
                p2 += __shfl_xor(p2, m);
                p3 += __shfl_xor(p3, m);
            }
            // transpose: this lane keeps the weight of batch-row `lo`
            int sl = (lo >> 2) * 16;
            float t0 = __shfl(p0, sl), t1 = __shfl(p1, sl);
            float t2 = __shfl(p2, sl), t3 = __shfl(p3, sl);
            int r = lo & 3;
            w_l[l] = (r == 0) ? t0 : (r == 1) ? t1 : (r == 2) ? t2 : t3;
        }
    }

    // ---------- phase 5: per-batch mask + softmax + weighted sum over value rows ----
    for (int t = 0; t < BPW; ++t) {
        long long b = b0w + t;
        long long bc = (b > (long long)B - 1) ? (long long)B - 1 : b;
        int sq = seq_len[bc];  // valid positions: l <= sq
        const float* vp = value + bc * (9 * 128) + lane * 2;
        f32x2 vv[9];
#pragma unroll
        for (int l = 0; l < 9; ++l) vv[l] = *(const f32x2*)(vp + l * 128);  // L2 hit
        float wl[9];
#pragma unroll
        for (int l = 0; l < 9; ++l) wl[l] = __shfl(w_l[l], t);
        float mx = -3e38f;
#pragma unroll
        for (int l = 0; l < 9; ++l) if (l <= sq) mx = fmaxf(mx, wl[l]);
        float e[9], s = 0.f;
#pragma unroll
        for (int l = 0; l < 9; ++l) { e[l] = (l <= sq) ? __expf(wl[l] - mx) : 0.f; s += e[l]; }
        float rs = 1.f / s;
        float ox = 0.f, oy = 0.f;
#pragma unroll
        for (int l = 0; l < 9; ++l) { ox += e[l] * vv[l].x; oy += e[l] * vv[l].y; }
        obuf[wave][t][lane] = pk_bf16(ox * rs, oy * rs);
    }

    __syncthreads();
    // ---------- phase 6: fcw fragments -> LDS (reuses wlds; first 1024 entries) ----
    stage_bfrags(fcw, 128, 0, 4, wlds, tid);
    __syncthreads();

    // ---------- phase 7: out = relu(O @ fcw^T + fcb), 16 batches per wave ----------
    {
        short8 af[4];
#pragma unroll
        for (int kt = 0; kt < 4; ++kt) {
            uint4v ov = *(const uint4v*)&obuf[wave][lo][kt * 16 + g * 4];
            af[kt] = __builtin_bit_cast(short8, ov);
        }
        f32x4 facc[4];
#pragma unroll
        for (int ct = 0; ct < 4; ++ct) {
            float fb = fcb[ct * 16 + lo];
            facc[ct] = (f32x4){fb, fb, fb, fb};
        }
#pragma unroll
        for (int kt = 0; kt < 4; ++kt)
#pragma unroll
            for (int ct = 0; ct < 4; ++ct)
                facc[ct] = __builtin_amdgcn_mfma_f32_16x16x32_bf16(
                    af[kt], wlds[(kt * 4 + ct) * 64 + lane], facc[ct], 0, 0, 0);
#pragma unroll
        for (int ct = 0; ct < 4; ++ct) {
            float v0 = fmaxf(facc[ct].x, 0.f), v1 = fmaxf(facc[ct].y, 0.f);
            float v2 = fmaxf(facc[ct].z, 0.f), v3 = fmaxf(facc[ct].w, 0.f);
            long long bo = b0w + g * 4;
            if (bo + 0 < B) out[(bo + 0) * 64 + ct * 16 + lo] = v0;
            if (bo + 1 < B) out[(bo + 1) * 64 + ct * 16 + lo] = v1;
            if (bo + 2 < B) out[(bo + 2) * 64 + ct * 16 + lo] = v2;
            if (bo + 3 < B) out[(bo + 3) * 64 + ct * 16 + lo] = v3;
        }
    }
}

extern "C" void kernel_launch(void* const* d_in, const int* in_sizes, int n_in,
                              void* d_out, int out_size, void* d_ws, size_t ws_size,
                              hipStream_t stream) {
    const float* value = (const float*)d_in[0];
    const float* key   = (const float*)d_in[1];
    const int*   seq   = (const int*)d_in[2];
    // d_in[3] = maxlen (unused; L == 9 fixed by reference)
    const float* w1    = (const float*)d_in[4];
    const float* b1    = (const float*)d_in[5];
    const float* w2    = (const float*)d_in[6];
    // d_in[7] = b2: softmax-invariant, dropped
    const float* fcw   = (const float*)d_in[8];
    const float* fcb   = (const float*)d_in[9];
    float* out = (float*)d_out;

    int B = in_sizes[1] / 128;
    int blocks = (B + BPB - 1) / BPB;
    mask_attn_fused<<<blocks, NW * 64, 0, stream>>>(value, key, seq, w1, b1, w2, fcw, fcb, out, B);
}